// Round 13
// baseline (99.054 us; speedup 1.0000x reference)
//
#include <hip/hip_runtime.h>
#include <math.h>

#define NUM_LEVELS 5
#define NUM_CLASSES 80
#define TOPK 1000
#define CAND_CAP 4096
#define NBINS 256
#define NREP 32
#define FLOORV 0.5f
#define BIN_W (0.5f / 256.0f)
#define INV_BIN_W (256.0f / 0.5f)
#define NROWS_TOTAL 349184

struct LevelParams {
    const float* cls[NUM_LEVELS];
    const float* box[NUM_LEVELS];
    const float* pss[NUM_LEVELS];
};

// Step-rounded f32 sigmoid, numpy scalar semantics (bit-matches golden; R6-R12 pass).
__device__ __forceinline__ float np_sigmoid_f32(float x) {
    float e32 = (float)exp(-(double)x);
    float d = __fadd_rn(1.0f, e32);
    return __fdiv_rn(1.0f, d);
}

__device__ __forceinline__ float max4(float4 a) {
    return fmaxf(fmaxf(a.x, a.y), fmaxf(a.z, a.w));
}

__device__ __forceinline__ int row_lev(int pid) {
    if (pid < 262144) return 0;
    if (pid < 327680) return 1;
    if (pid < 344064) return 2;
    if (pid < 348160) return 3;
    return 4;
}
__constant__ int c_rowoff[5] = {0, 262144, 327680, 344064, 348160};

// bid<40: zero histR (10240 float4) + count. bid>=40: per-row prep:
// meta[r] = {cthr0, A}: A = 1+e^-p; c >= cthr0 <=> s >= 0.5 (conservative margin).
__global__ __launch_bounds__(256) void k_zero_prep(LevelParams P, float4* histR4, int* count,
                                                   float2* meta) {
    const int bid = blockIdx.x;
    if (bid < 40) {
        int i = bid * 256 + threadIdx.x;
        histR4[i] = make_float4(0.f, 0.f, 0.f, 0.f);
        if (i < NUM_LEVELS) count[i] = 0;
        return;
    }
    int pid = (bid - 40) * 256 + (int)threadIdx.x;   // exact: (1404-40)*256 == 349184
    int lev = row_lev(pid);
    float p = P.pss[lev][pid - c_rowoff[lev]];
    float A = 1.0f + __expf(-p);
    float g2 = 2.0f * __frcp_rn(A) - 1.0f;           // e^-c <= g2 <=> s >= 0.5
    float cthr0 = (g2 > 0.0f) ? (-__logf(g2) - 1e-2f) : 1e30f;  // conservative c-margin
    meta[pid] = make_float2(cthr0, A);
}

// Lane-coalesced cls stream. Per float4: compare-only floor test; rare inner bins.
// m8[chunk] = exact raw max of 8 cls (via shfl pair-merge), coalesced 4B stores.
__global__ __launch_bounds__(256, 8) void k_hist(LevelParams P, const float2* meta,
                                                 unsigned* histR, float* m8) {
    __shared__ unsigned lh[NBINS];
    for (int i = threadIdx.x; i < NBINS; i += 256) lh[i] = 0;
    __syncthreads();

    const int bid = blockIdx.x;
    int lev, lb, nb, G;
    if (bid < 1536)      { lev = 0; lb = bid;        nb = 1536; G = 5120; }
    else if (bid < 1920) { lev = 1; lb = bid - 1536; nb = 384;  G = 1280; }
    else if (bid < 2016) { lev = 2; lb = bid - 1920; nb = 96;   G = 320;  }
    else if (bid < 2040) { lev = 3; lb = bid - 2016; nb = 24;   G = 80;   }
    else                 { lev = 4; lb = bid - 2040; nb = 8;    G = 20;   }

    const float4* __restrict__ cls4 = (const float4*)P.cls[lev];
    const float2* __restrict__ meta_l = meta + c_rowoff[lev];
    float* __restrict__ m8_l = m8 + ((size_t)c_rowoff[lev] * 10);  // 10 chunks/row
    const int t = (int)threadIdx.x;

    for (int g = lb; g < G; g += nb) {
        int i4base = g * 1024 + t;
#pragma unroll
        for (int s = 0; s < 4; ++s) {
            int i4 = i4base + s * 256;          // level-local float4 index (coalesced)
            float4 c = cls4[i4];
            float m = max4(c);
            int r = i4 / 20;                    // 20 float4s per 80-class row
            float2 md = meta_l[r];
            float m8v = fmaxf(m, __shfl_xor(m, 1));
            if ((t & 1) == 0) m8_l[i4 >> 1] = m8v;
            if (m >= md.x) {                    // floor pass (~6.5% of elems)
                float cs[4] = {c.x, c.y, c.z, c.w};
#pragma unroll
                for (int j = 0; j < 4; ++j) {
                    float E = __expf(-cs[j]);
                    if (fmaf(E, md.y, md.y) <= 2.0f) {   // (1+E)*A <= 2
                        float sc = __frcp_rn((1.0f + E) * md.y);
                        int b = (int)((sc - FLOORV) * INV_BIN_W);
                        if (b < 0) b = 0;
                        if (b > NBINS - 1) b = NBINS - 1;
                        atomicAdd(&lh[b], 1u);
                    }
                }
            }
        }
    }

    __syncthreads();
    unsigned* h = histR + (size_t)(bid & (NREP - 1)) * (NUM_LEVELS * NBINS) + lev * NBINS;
    for (int i = threadIdx.x; i < NBINS; i += 256) {
        unsigned v = lh[i];
        if (v) atomicAdd(&h[i], v);
    }
}

__global__ __launch_bounds__(256) void k_cutoff(const unsigned* histR, float* cutL) {
    __shared__ unsigned sh[NBINS];
    const int lev = blockIdx.x;
    unsigned s = 0;
#pragma unroll
    for (int r = 0; r < NREP; ++r)
        s += histR[(size_t)r * (NUM_LEVELS * NBINS) + lev * NBINS + threadIdx.x];
    sh[threadIdx.x] = s;
    __syncthreads();
    if (threadIdx.x == 0) {
        long cum = 0;
        int b = NBINS - 1;
        for (; b >= 0; --b) {
            cum += sh[b];
            if (cum >= TOPK) break;
        }
        int sel = (b <= 0) ? 0 : (b - 1);  // one margin bin below crossing
        cutL[lev] = FLOORV + (float)sel * BIN_W;
    }
}

// Per-row cutoff threshold in c-space: c >= cthrL[r] <=> s >= cutL (conservative).
__global__ __launch_bounds__(256) void k_prep2(const float2* meta, const float* cutL,
                                               float* cthrL) {
    int pid = blockIdx.x * 256 + (int)threadIdx.x;   // 1364*256 == 349184 exact
    int lev = row_lev(pid);
    float thr = cutL[lev] - 1e-4f;
    float A = meta[pid].y;
    float gg = __frcp_rn(thr * A) - 1.0f;            // e^-c <= gg <=> s >= thr
    cthrL[pid] = (gg > 0.0f) ? (-__logf(gg) - 1e-2f) : 1e30f;
}

// Scan m8 (coalesced, 14MB) vs cthrL; only passing chunks gather cls.
__global__ __launch_bounds__(256) void k_compact(LevelParams P, const float* cthrL,
                                                 const float* m8, int* count, int* cand) {
    const int bid = blockIdx.x;
    int lev, bstart;
    if (bid < 10240)      { lev = 0; bstart = 0; }
    else if (bid < 12800) { lev = 1; bstart = 10240; }
    else if (bid < 13440) { lev = 2; bstart = 12800; }
    else if (bid < 13600) { lev = 3; bstart = 13440; }
    else                  { lev = 4; bstart = 13600; }

    const int cid = (bid - bstart) * 256 + (int)threadIdx.x;    // level-local 8-chunk
    const float* __restrict__ m8_l = m8 + ((size_t)c_rowoff[lev] * 10);
    const float* __restrict__ cthrL_l = cthrL + c_rowoff[lev];
    float mv = m8_l[cid];
    float ct = cthrL_l[cid / 10];
    bool pass = mv >= ct;
    if (__syncthreads_count(pass) == 0) return;

    __shared__ int lcount;
    __shared__ int lbase;
    __shared__ int lbuf[2048];
    if (threadIdx.x == 0) lcount = 0;
    __syncthreads();

    if (pass) {
        const float* __restrict__ cls = P.cls[lev];
        const int el = cid * 8;
        float4 c0 = *(const float4*)(cls + el);
        float4 c1 = *(const float4*)(cls + el + 4);
        float cs[8] = {c0.x, c0.y, c0.z, c0.w, c1.x, c1.y, c1.z, c1.w};
#pragma unroll
        for (int j = 0; j < 8; ++j) {
            if (cs[j] >= ct) {
                int li = atomicAdd(&lcount, 1);
                if (li < 2048) lbuf[li] = el + j;
            }
        }
    }
    __syncthreads();
    if (threadIdx.x == 0) lbase = atomicAdd(&count[lev], lcount);  // ONE global atomic/block
    __syncthreads();
    const int m = lcount < 2048 ? lcount : 2048;
    const int base = lbase;
    for (int i = threadIdx.x; i < m; i += 256) {
        int pos = base + i;
        if (pos < CAND_CAP) cand[lev * CAND_CAP + pos] = lbuf[i];
    }
}

__global__ __launch_bounds__(1024) void k_final(LevelParams P, const int* cand, const int* count,
                                                const int* wptr, const int* hptr, float* out) {
    // Packed u64 keys: (f32 score bits << 32) | (0xFFFFFFFF - idx).
    // Descending u64 sort == descending score, ties -> ascending index.
    __shared__ unsigned long long sk[CAND_CAP];
    const int lev = blockIdx.x;
    int n = count[lev];
    if (n > CAND_CAP) n = CAND_CAP;
    int size = 1024;
    while (size < n) size <<= 1;  // 1024 / 2048 / 4096

    const float* __restrict__ cls = P.cls[lev];
    const float* __restrict__ pss = P.pss[lev];
    const float* __restrict__ box = P.box[lev];

    for (int i = threadIdx.x; i < size; i += 1024) {
        if (i < n) {
            int idx = cand[lev * CAND_CAP + i];
            float a32 = np_sigmoid_f32(cls[idx]);
            float b32 = np_sigmoid_f32(pss[idx / NUM_CLASSES]);
            float s = __fmul_rn(a32, b32);
            sk[i] = ((unsigned long long)(unsigned)__float_as_int(s) << 32)
                    | (unsigned long long)(0xFFFFFFFFu - (unsigned)idx);
        } else {
            sk[i] = 0ull;
        }
    }
    __syncthreads();

    for (int k = 2; k <= size; k <<= 1) {
        for (int j = k >> 1; j > 0; j >>= 1) {
            for (int t = threadIdx.x; t < (size >> 1); t += 1024) {
                int i = ((t & ~(j - 1)) << 1) | (t & (j - 1));
                int ix = i | j;
                unsigned long long a = sk[i], b = sk[ix];
                bool dirDesc = ((i & k) == 0);
                if ((a > b) != dirDesc) {
                    sk[i] = b; sk[ix] = a;
                }
            }
            __syncthreads();
        }
    }

    const float w = (float)wptr[0], h = (float)hptr[0];
    const float invw = 1.0f / w, invh = 1.0f / h;
    for (int r = threadIdx.x; r < TOPK; r += 1024) {
        unsigned long long v = sk[r];
        float s = __int_as_float((int)(unsigned)(v >> 32));
        int idx = (int)(0xFFFFFFFFu - (unsigned)(v & 0xFFFFFFFFull));
        bool keep = (r < n) && (s > 0.05f);
        int row = lev * TOPK + r;
        float b0 = 0.f, b1 = 0.f, b2 = 0.f, b3 = 0.f;
        if (keep) {
            int a = idx / NUM_CLASSES;
            b0 = fminf(fmaxf(box[a * 4 + 0] * invw, 0.f), 1.f);
            b1 = fminf(fmaxf(box[a * 4 + 1] * invh, 0.f), 1.f);
            b2 = fminf(fmaxf(box[a * 4 + 2] * invw, 0.f), 1.f);
            b3 = fminf(fmaxf(box[a * 4 + 3] * invh, 0.f), 1.f);
        }
        out[row * 4 + 0] = b0;
        out[row * 4 + 1] = b1;
        out[row * 4 + 2] = b2;
        out[row * 4 + 3] = b3;
        out[NUM_LEVELS * TOPK * 4 + row] = keep ? s : 0.0f;
        out[NUM_LEVELS * TOPK * 5 + row] = keep ? (float)(idx % NUM_CLASSES) : -1.0f;
    }
}

extern "C" void kernel_launch(void* const* d_in, const int* in_sizes, int n_in,
                              void* d_out, int out_size, void* d_ws, size_t ws_size,
                              hipStream_t stream) {
    LevelParams P;
    for (int i = 0; i < NUM_LEVELS; ++i) {
        P.cls[i] = (const float*)d_in[3 * i + 0];
        P.box[i] = (const float*)d_in[3 * i + 1];
        P.pss[i] = (const float*)d_in[3 * i + 2];
    }
    const int* wp = (const int*)d_in[15];
    const int* hp = (const int*)d_in[16];

    unsigned char* ws = (unsigned char*)d_ws;
    unsigned* histR = (unsigned*)ws;                 // [0, 163840)
    float* cutL = (float*)(ws + 163840);             // 20 B
    int* count = (int*)(ws + 163860);                // 20 B
    float2* meta = (float2*)(ws + 163904);           // 349184*8 = 2793472 -> ends 2957376
    float* cthrL = (float*)(ws + 2957376);           // 349184*4 = 1396736 -> ends 4354112
    float* m8 = (float*)(ws + 4354112);              // 3491840*4 = 13967360 -> ends 18321472
    int* cand = (int*)(ws + 18321472);               // 81920

    k_zero_prep<<<1404, 256, 0, stream>>>(P, (float4*)histR, count, meta);
    k_hist<<<2048, 256, 0, stream>>>(P, meta, histR, m8);
    k_cutoff<<<NUM_LEVELS, 256, 0, stream>>>(histR, cutL);
    k_prep2<<<1364, 256, 0, stream>>>(meta, cutL, cthrL);
    k_compact<<<13640, 256, 0, stream>>>(P, cthrL, m8, count, cand);
    k_final<<<NUM_LEVELS, 1024, 0, stream>>>(P, cand, count, wp, hp, (float*)d_out);
}

// Round 14
// 93.401 us; speedup vs baseline: 1.0605x; 1.0605x over previous
//
#include <hip/hip_runtime.h>
#include <math.h>

#define NUM_LEVELS 5
#define NUM_CLASSES 80
#define TOPK 1000
#define CAND_CAP 4096
#define NBINS 1024
#define NREP 16
#define FLOORV 0.375f
#define BIN_W (0.625f / 1024.0f)
#define INV_BIN_W (1024.0f / 0.625f)

struct LevelParams {
    const float* cls[NUM_LEVELS];
    const float* box[NUM_LEVELS];
    const float* pss[NUM_LEVELS];
};

// Step-rounded f32 sigmoid, numpy scalar semantics (bit-matches golden; R6-R13 pass).
__device__ __forceinline__ float np_sigmoid_f32(float x) {
    float e32 = (float)exp(-(double)x);
    float d = __fadd_rn(1.0f, e32);
    return __fdiv_rn(1.0f, d);
}

__device__ __forceinline__ float max4(float4 a) {
    return fmaxf(fmaxf(a.x, a.y), fmaxf(a.z, a.w));
}

// bid<80: zero histR (16*5*1024 u32 = 20480 float4) + count.
// bid>=80: per-row meta: {cthr0, A}; c >= cthr0 <=> s >= 0.375 (conservative).
__global__ __launch_bounds__(256) void k_zero_prep(LevelParams P, float4* histR4, int* count,
                                                   float2* meta) {
    const int bid = blockIdx.x;
    if (bid < 80) {
        int i = bid * 256 + threadIdx.x;
        histR4[i] = make_float4(0.f, 0.f, 0.f, 0.f);
        if (i < NUM_LEVELS) count[i] = 0;
        return;
    }
    int pid = (bid - 80) * 256 + (int)threadIdx.x;   // (1444-80)*256 == 349184 exact
    int lev, off;
    if (pid < 262144)      { lev = 0; off = 0; }
    else if (pid < 327680) { lev = 1; off = 262144; }
    else if (pid < 344064) { lev = 2; off = 327680; }
    else if (pid < 348160) { lev = 3; off = 344064; }
    else                   { lev = 4; off = 348160; }
    float p = P.pss[lev][pid - off];
    float A = 1.0f + __expf(-p);
    float gF = __frcp_rn(FLOORV * A) - 1.0f;          // e^-c <= gF <=> s >= FLOORV
    float cthr0 = (gF > 0.0f) ? (-__logf(gF) - 1e-2f) : 1e30f;
    meta[pid] = make_float2(cthr0, A);
}

// Hot loop: load float4 -> max4 -> shfl-pair -> even lanes store m8 + compare.
// Only chunks with max >= cthr0 (rare) compute exp/rcp/bin/atomic.
// Contiguous per-block slabs of 256-float4 steps.
__global__ __launch_bounds__(256) void k_hist(LevelParams P, const float2* meta,
                                              unsigned* histR, float* m8) {
    __shared__ unsigned lh[NBINS];
    for (int i = threadIdx.x; i < NBINS; i += 256) lh[i] = 0;
    __syncthreads();

    const int bid = blockIdx.x;
    // steps per level: {20480,5120,1280,320,80}; blocks {1536,384,96,24,8}
    int lev, lb, q, r, roff;
    if (bid < 1536)      { lev = 0; lb = bid;        q = 13; r = 512; roff = 0; }
    else if (bid < 1920) { lev = 1; lb = bid - 1536; q = 13; r = 128; roff = 262144; }
    else if (bid < 2016) { lev = 2; lb = bid - 1920; q = 13; r = 32;  roff = 327680; }
    else if (bid < 2040) { lev = 3; lb = bid - 2016; q = 13; r = 8;   roff = 344064; }
    else                 { lev = 4; lb = bid - 2040; q = 10; r = 0;   roff = 348160; }
    const int start = lb * q + (lb < r ? lb : r);
    const int cnt = q + (lb < r ? 1 : 0);

    const float4* __restrict__ cls4 = (const float4*)P.cls[lev];
    const float2* __restrict__ meta_l = meta + roff;
    float* __restrict__ m8_l = m8 + (size_t)roff * 10;   // 10 chunks per row
    const int t = (int)threadIdx.x;

    int i4 = start * 256 + t;
    float4 c = cls4[i4];
    for (int it = 0; it < cnt; ++it) {
        int i4n = i4 + 256;
        float4 cn;
        if (it + 1 < cnt) cn = cls4[i4n];      // uniform branch, 2-deep pipeline

        float m = max4(c);
        float m2 = fmaxf(m, __shfl_xor(m, 1));
        if ((t & 1) == 0) {
            int chunk = i4 >> 1;
            m8_l[chunk] = m2;
            int row = chunk / 10;
            float2 md = meta_l[row];
            if (m2 >= md.x) {                  // floor pass: rare
                float E = __expf(-m2);
                float sc = __frcp_rn((1.0f + E) * md.y);
                int b = (int)((sc - FLOORV) * INV_BIN_W);
                if (b < 0) b = 0;
                if (b > NBINS - 1) b = NBINS - 1;
                atomicAdd(&lh[b], 1u);
            }
        }
        i4 = i4n; c = cn;
    }

    __syncthreads();
    unsigned* h = histR + (size_t)(bid & (NREP - 1)) * (NUM_LEVELS * NBINS) + lev * NBINS;
    for (int i = threadIdx.x; i < NBINS; i += 256) {
        unsigned v = lh[i];
        if (v) atomicAdd(&h[i], v);
    }
}

__global__ __launch_bounds__(256) void k_cutoff(const unsigned* histR, float* cutL) {
    __shared__ unsigned sh[NBINS];
    __shared__ unsigned ps[256];
    const int lev = blockIdx.x;
    const int tid = (int)threadIdx.x;
    unsigned seg = 0;
    for (int j = 0; j < 4; ++j) {
        int b = tid * 4 + j;
        unsigned s = 0;
#pragma unroll
        for (int rp = 0; rp < NREP; ++rp)
            s += histR[(size_t)rp * (NUM_LEVELS * NBINS) + lev * NBINS + b];
        sh[b] = s;
        seg += s;
    }
    ps[tid] = seg;
    __syncthreads();
    if (tid == 0) {
        long cum = 0;
        int sgi = 255;
        for (; sgi >= 0; --sgi) {
            if (cum + ps[sgi] >= TOPK) break;
            cum += ps[sgi];
        }
        int b = 0;
        if (sgi >= 0) {
            b = sgi * 4;
            for (int j = sgi * 4 + 3; j >= sgi * 4; --j) {
                cum += sh[j];
                if (cum >= TOPK) { b = j; break; }
            }
        }
        int sel = (b <= 0) ? 0 : (b - 1);      // one margin bin below crossing
        cutL[lev] = FLOORV + (float)sel * BIN_W;
    }
}

// Scan m8 (14MB coalesced) vs per-row c-space cutoff (computed inline from meta).
__global__ __launch_bounds__(256) void k_compact(LevelParams P, const float* cutL,
                                                 const float2* meta, const float* m8,
                                                 int* count, int* cand) {
    const int bid = blockIdx.x;
    int lev, bstart, roff;
    if (bid < 10240)      { lev = 0; bstart = 0;     roff = 0; }
    else if (bid < 12800) { lev = 1; bstart = 10240; roff = 262144; }
    else if (bid < 13440) { lev = 2; bstart = 12800; roff = 327680; }
    else if (bid < 13600) { lev = 3; bstart = 13440; roff = 344064; }
    else                  { lev = 4; bstart = 13600; roff = 348160; }

    const int cid = (bid - bstart) * 256 + (int)threadIdx.x;   // level-local chunk
    const float* __restrict__ m8_l = m8 + (size_t)roff * 10;
    const float2* __restrict__ meta_l = meta + roff;
    float mv = m8_l[cid];
    float2 md = meta_l[cid / 10];
    const float thr = cutL[lev] - 1e-4f;
    float gg = __frcp_rn(thr * md.y) - 1.0f;            // e^-c <= gg <=> s >= thr
    float ct = (gg > 0.0f) ? (-__logf(gg) - 1e-2f) : 1e30f;
    bool pass = mv >= ct;
    if (__syncthreads_count(pass) == 0) return;

    __shared__ int lcount;
    __shared__ int lbase;
    __shared__ int lbuf[2048];
    if (threadIdx.x == 0) lcount = 0;
    __syncthreads();

    if (pass) {
        const float* __restrict__ cls = P.cls[lev];
        const int el = cid * 8;
        float4 c0 = *(const float4*)(cls + el);
        float4 c1 = *(const float4*)(cls + el + 4);
        float cs[8] = {c0.x, c0.y, c0.z, c0.w, c1.x, c1.y, c1.z, c1.w};
#pragma unroll
        for (int j = 0; j < 8; ++j) {
            if (cs[j] >= ct) {
                int li = atomicAdd(&lcount, 1);
                if (li < 2048) lbuf[li] = el + j;
            }
        }
    }
    __syncthreads();
    if (threadIdx.x == 0) lbase = atomicAdd(&count[lev], lcount);  // ONE global atomic/block
    __syncthreads();
    const int m = lcount < 2048 ? lcount : 2048;
    const int base = lbase;
    for (int i = threadIdx.x; i < m; i += 256) {
        int pos = base + i;
        if (pos < CAND_CAP) cand[lev * CAND_CAP + pos] = lbuf[i];
    }
}

__global__ __launch_bounds__(1024) void k_final(LevelParams P, const int* cand, const int* count,
                                                const int* wptr, const int* hptr, float* out) {
    // Packed u64 keys: (f32 score bits << 32) | (0xFFFFFFFF - idx).
    // Descending u64 sort == descending score, ties -> ascending index.
    __shared__ unsigned long long sk[CAND_CAP];
    const int lev = blockIdx.x;
    int n = count[lev];
    if (n > CAND_CAP) n = CAND_CAP;
    int size = 1024;
    while (size < n) size <<= 1;  // 1024 / 2048 / 4096

    const float* __restrict__ cls = P.cls[lev];
    const float* __restrict__ pss = P.pss[lev];
    const float* __restrict__ box = P.box[lev];

    for (int i = threadIdx.x; i < size; i += 1024) {
        if (i < n) {
            int idx = cand[lev * CAND_CAP + i];
            float a32 = np_sigmoid_f32(cls[idx]);
            float b32 = np_sigmoid_f32(pss[idx / NUM_CLASSES]);
            float s = __fmul_rn(a32, b32);
            sk[i] = ((unsigned long long)(unsigned)__float_as_int(s) << 32)
                    | (unsigned long long)(0xFFFFFFFFu - (unsigned)idx);
        } else {
            sk[i] = 0ull;
        }
    }
    __syncthreads();

    for (int k = 2; k <= size; k <<= 1) {
        for (int j = k >> 1; j > 0; j >>= 1) {
            for (int t = threadIdx.x; t < (size >> 1); t += 1024) {
                int i = ((t & ~(j - 1)) << 1) | (t & (j - 1));
                int ix = i | j;
                unsigned long long a = sk[i], b = sk[ix];
                bool dirDesc = ((i & k) == 0);
                if ((a > b) != dirDesc) {
                    sk[i] = b; sk[ix] = a;
                }
            }
            __syncthreads();
        }
    }

    const float w = (float)wptr[0], h = (float)hptr[0];
    const float invw = 1.0f / w, invh = 1.0f / h;
    for (int r = threadIdx.x; r < TOPK; r += 1024) {
        unsigned long long v = sk[r];
        float s = __int_as_float((int)(unsigned)(v >> 32));
        int idx = (int)(0xFFFFFFFFu - (unsigned)(v & 0xFFFFFFFFull));
        bool keep = (r < n) && (s > 0.05f);
        int row = lev * TOPK + r;
        float b0 = 0.f, b1 = 0.f, b2 = 0.f, b3 = 0.f;
        if (keep) {
            int a = idx / NUM_CLASSES;
            b0 = fminf(fmaxf(box[a * 4 + 0] * invw, 0.f), 1.f);
            b1 = fminf(fmaxf(box[a * 4 + 1] * invh, 0.f), 1.f);
            b2 = fminf(fmaxf(box[a * 4 + 2] * invw, 0.f), 1.f);
            b3 = fminf(fmaxf(box[a * 4 + 3] * invh, 0.f), 1.f);
        }
        out[row * 4 + 0] = b0;
        out[row * 4 + 1] = b1;
        out[row * 4 + 2] = b2;
        out[row * 4 + 3] = b3;
        out[NUM_LEVELS * TOPK * 4 + row] = keep ? s : 0.0f;
        out[NUM_LEVELS * TOPK * 5 + row] = keep ? (float)(idx % NUM_CLASSES) : -1.0f;
    }
}

extern "C" void kernel_launch(void* const* d_in, const int* in_sizes, int n_in,
                              void* d_out, int out_size, void* d_ws, size_t ws_size,
                              hipStream_t stream) {
    LevelParams P;
    for (int i = 0; i < NUM_LEVELS; ++i) {
        P.cls[i] = (const float*)d_in[3 * i + 0];
        P.box[i] = (const float*)d_in[3 * i + 1];
        P.pss[i] = (const float*)d_in[3 * i + 2];
    }
    const int* wp = (const int*)d_in[15];
    const int* hp = (const int*)d_in[16];

    unsigned char* ws = (unsigned char*)d_ws;
    unsigned* histR = (unsigned*)ws;                 // 16*5*1024*4 = 327680   [0, 327680)
    float* cutL = (float*)(ws + 327680);             // 20 B
    int* count = (int*)(ws + 327700);                // 20 B
    float2* meta = (float2*)(ws + 327744);           // 349184*8 = 2793472 -> ends 3121216
    float* m8 = (float*)(ws + 3121216);              // 3491840*4 = 13967360 -> ends 17088576
    int* cand = (int*)(ws + 17088576);               // 81920

    k_zero_prep<<<1444, 256, 0, stream>>>(P, (float4*)histR, count, meta);
    k_hist<<<2048, 256, 0, stream>>>(P, meta, histR, m8);
    k_cutoff<<<NUM_LEVELS, 256, 0, stream>>>(histR, cutL);
    k_compact<<<13640, 256, 0, stream>>>(P, cutL, meta, m8, count, cand);
    k_final<<<NUM_LEVELS, 1024, 0, stream>>>(P, cand, count, wp, hp, (float*)d_out);
}